// Round 5
// baseline (385.285 us; speedup 1.0000x reference)
//
#include <hip/hip_runtime.h>
#include <hip/hip_bf16.h>

typedef short short8 __attribute__((ext_vector_type(8)));
typedef short short4v __attribute__((ext_vector_type(4)));
typedef float floatx4 __attribute__((ext_vector_type(4)));

constexpr int Bc = 2, Sc = 4096, Dc = 512, Hc = 8, DKc = 64;
constexpr int Mc = Bc * Sc;  // 8192

static __device__ __forceinline__ unsigned short f2bf(float f) {
  unsigned int u = __builtin_bit_cast(unsigned int, f);
  unsigned int rb = ((u >> 16) & 1u) + 0x7fffu;
  return (unsigned short)((u + rb) >> 16);
}
static __device__ __forceinline__ unsigned int pack_bf2(float a, float b) {
  return (unsigned int)f2bf(a) | ((unsigned int)f2bf(b) << 16);
}

// ---------------- weight cast ------------------------------------------------
__global__ __launch_bounds__(256) void cast_w(
    const float* __restrict__ a, const float* __restrict__ b,
    const float* __restrict__ c, const float* __restrict__ d,
    unsigned short* __restrict__ out) {
  const float* srcs[4] = {a, b, c, d};
  const int m = blockIdx.y;
  const int i = (blockIdx.x * 256 + threadIdx.x) * 4;
  float4 v = *(const float4*)(srcs[m] + i);
  unsigned short t4[4] = {f2bf(v.x), f2bf(v.y), f2bf(v.z), f2bf(v.w)};
  *(short4v*)(out + (size_t)m * (Dc * Dc) + i) = *(short4v*)t4;
}

// ---------------- GEMM: Y[M,N] = X[M,K] @ W[N,K]^T ---------------------------
template <int IN_F32, int OUT_F32>
__global__ __launch_bounds__(256) void gemm_bt(
    const void* __restrict__ Xv, const unsigned short* __restrict__ Wb,
    void* __restrict__ Yv, int Mdim, int N, int K) {
  constexpr int BM = 128, BN = 128, BK = 32, LDP = 40;
  __shared__ unsigned short As[BM * LDP];
  __shared__ unsigned short Bs[BN * LDP];
  const int tid = threadIdx.x;
  const int lane = tid & 63, wid = tid >> 6;
  const int wm = wid >> 1, wn = wid & 1;
  const int bm = blockIdx.y * BM, bn = blockIdx.x * BN;
  const int rq = lane & 15, kk8 = (lane >> 4) * 8;
  const int sr = tid >> 1;
  const int sc = (tid & 1) * 16;

  floatx4 acc[4][4] = {};

  for (int k0 = 0; k0 < K; k0 += BK) {
    if (IN_F32) {
      const float* src = (const float*)Xv + (size_t)(bm + sr) * K + k0 + sc;
      unsigned short tmp[16];
#pragma unroll
      for (int i = 0; i < 4; ++i) {
        float4 v = *(const float4*)(src + i * 4);
        tmp[i * 4 + 0] = f2bf(v.x);
        tmp[i * 4 + 1] = f2bf(v.y);
        tmp[i * 4 + 2] = f2bf(v.z);
        tmp[i * 4 + 3] = f2bf(v.w);
      }
      *(short8*)&As[sr * LDP + sc] = *(short8*)&tmp[0];
      *(short8*)&As[sr * LDP + sc + 8] = *(short8*)&tmp[8];
    } else {
      const unsigned short* src =
          (const unsigned short*)Xv + (size_t)(bm + sr) * K + k0 + sc;
      *(short8*)&As[sr * LDP + sc] = *(const short8*)src;
      *(short8*)&As[sr * LDP + sc + 8] = *(const short8*)(src + 8);
    }
    const unsigned short* bsrc = Wb + (size_t)(bn + sr) * K + k0 + sc;
    *(short8*)&Bs[sr * LDP + sc] = *(const short8*)bsrc;
    *(short8*)&Bs[sr * LDP + sc + 8] = *(const short8*)(bsrc + 8);
    __syncthreads();

    short8 af[4], bfr[4];
#pragma unroll
    for (int mi = 0; mi < 4; ++mi)
      af[mi] = *(const short8*)&As[(wm * 64 + mi * 16 + rq) * LDP + kk8];
#pragma unroll
    for (int ni = 0; ni < 4; ++ni)
      bfr[ni] = *(const short8*)&Bs[(wn * 64 + ni * 16 + rq) * LDP + kk8];
#pragma unroll
    for (int mi = 0; mi < 4; ++mi)
#pragma unroll
      for (int ni = 0; ni < 4; ++ni)
        acc[mi][ni] = __builtin_amdgcn_mfma_f32_16x16x32_bf16(
            af[mi], bfr[ni], acc[mi][ni], 0, 0, 0);
    __syncthreads();
  }

#pragma unroll
  for (int mi = 0; mi < 4; ++mi)
#pragma unroll
    for (int ni = 0; ni < 4; ++ni)
#pragma unroll
      for (int j = 0; j < 4; ++j) {
        int r = bm + wm * 64 + mi * 16 + (lane >> 4) * 4 + j;
        int c = bn + wn * 64 + ni * 16 + rq;
        float v = acc[mi][ni][j];
        if (OUT_F32)
          ((float*)Yv)[(size_t)r * N + c] = v;
        else
          ((unsigned short*)Yv)[(size_t)r * N + c] = f2bf(v);
      }
}

// ---------------- V transpose: vt[b][c][s] = vb[b][s][c] ---------------------
__global__ __launch_bounds__(256) void transpose_v(
    const unsigned short* __restrict__ vb, unsigned short* __restrict__ vt) {
  constexpr int LDT = 65;
  __shared__ unsigned short T[64 * LDT];
  const int tid = threadIdx.x;
  const int s0 = blockIdx.x * 64, c0 = blockIdx.y * 64, b = blockIdx.z;
  const int r = tid >> 2, cs = (tid & 3) * 16;
  const unsigned short* src = vb + ((size_t)b * Sc + s0 + r) * Dc + c0 + cs;
  *(short8*)&T[r * LDT + cs] = *(const short8*)src;
  *(short8*)&T[r * LDT + cs + 8] = *(const short8*)(src + 8);
  __syncthreads();
  unsigned short* dst = vt + ((size_t)b * Dc + c0 + r) * Sc + s0 + cs;
  unsigned short tmp[16];
#pragma unroll
  for (int j = 0; j < 16; ++j) tmp[j] = T[(cs + j) * LDT + r];
  *(short8*)dst = *(short8*)&tmp[0];
  *(short8*)(dst + 8) = *(short8*)&tmp[8];
}

// ---------------- flash attention (k-split, swapped QK^T) --------------------
// 512 threads = 8 waves; group g = key-half; wave w owns 32 q-rows.
// Swapped QK^T: s = mfma(K_frag, Q_frag) -> lane holds 16 scores for q=lane&15.
__global__ __launch_bounds__(512, 6) void attn_fwd(
    const unsigned short* __restrict__ Qp, const unsigned short* __restrict__ Kp,
    const unsigned short* __restrict__ Vtp, unsigned short* __restrict__ Op) {
  constexpr int KB = 64, LDPS = 72;
  // LDS map (bytes): Ks [0,16384) 2g x [64][64] swz; Vs [16384,32768) same;
  // Ps [32768,51200) 2g x 4w x [16][72]. Merge overlay: MO f32[128][64] @0,
  // ML f32[128][2] @32768.
  __shared__ unsigned char smem[51200];
  unsigned short* KsB = (unsigned short*)smem;
  unsigned short* VsB = (unsigned short*)(smem + 16384);
  unsigned short* PsB = (unsigned short*)(smem + 32768);

  const int tid = threadIdx.x, lane = tid & 63, wid = tid >> 6;
  const int g = wid >> 2, w = wid & 3;
  const int b = blockIdx.y >> 3, h = blockIdx.y & 7;
  const int q0 = blockIdx.x * 128 + w * 32;
  const int rq = lane & 15, lg = lane >> 4, kk8 = lg * 8;

  unsigned short* Ksg = KsB + g * 4096;
  unsigned short* Vsg = VsB + g * 4096;
  unsigned short* Psw = PsB + (g * 4 + w) * (16 * LDPS);

  const unsigned short* Qb = Qp + ((size_t)b * Sc) * Dc + h * DKc;
  const unsigned short* Kb = Kp + ((size_t)b * Sc) * Dc + h * DKc;
  const unsigned short* Vh = Vtp + ((size_t)b * Dc + h * DKc) * Sc;

  // Q as B-fragment: col=lane&15=q, k=(lane>>4)*8+j  (row-wise load)
  short8 qa[2][2];
#pragma unroll
  for (int qi = 0; qi < 2; ++qi)
#pragma unroll
    for (int c = 0; c < 2; ++c)
      qa[qi][c] = *(const short8*)(Qb + (size_t)(q0 + qi * 16 + rq) * Dc + c * 32 + kk8);

  floatx4 o_acc[2][4] = {};
  floatx4 acc_l[2] = {};
  float m_run[2] = {-1e30f, -1e30f};  // per-lane, q = lane&15 (x4 replicas)

  short8 ones;
#pragma unroll
  for (int j = 0; j < 8; ++j) ones[j] = (short)0x3F80;

  const float C1 = 0.125f;  // 1/sqrt(64)

  // staging map: 256 threads/group stage 64 rows x 64 cols, XOR granule swizzle
  const int u = tid & 255;
  const int sr = u >> 2, sc16 = (u & 3) * 16;
  const int st0 = (sr * 64 + sc16) ^ ((sr & 7) << 3);
  const int st1 = (sr * 64 + sc16 + 8) ^ ((sr & 7) << 3);

  for (int it = 0; it < Sc / 2 / KB; ++it) {
    const int k0 = g * (Sc / 2) + it * KB;
    {
      const unsigned short* ks = Kb + (size_t)(k0 + sr) * Dc + sc16;
      *(short8*)&Ksg[st0] = *(const short8*)ks;
      *(short8*)&Ksg[st1] = *(const short8*)(ks + 8);
      const unsigned short* vs = Vh + (size_t)sr * Sc + k0 + sc16;
      *(short8*)&Vsg[st0] = *(const short8*)vs;
      *(short8*)&Vsg[st1] = *(const short8*)(vs + 8);
    }
    __syncthreads();

#pragma unroll
    for (int qi = 0; qi < 2; ++qi) {
      // swapped QK^T: s4[kt][j] = S[q=rq][key = kt*16 + lg*4 + j]
      floatx4 s4[4] = {};
#pragma unroll
      for (int kt = 0; kt < 4; ++kt) {
        const int row = kt * 16 + rq, sx = (rq & 7) << 3;
        short8 a0 = *(const short8*)&Ksg[(row * 64 + kk8) ^ sx];
        short8 a1 = *(const short8*)&Ksg[(row * 64 + 32 + kk8) ^ sx];
        s4[kt] = __builtin_amdgcn_mfma_f32_16x16x32_bf16(a0, qa[qi][0], s4[kt], 0, 0, 0);
        s4[kt] = __builtin_amdgcn_mfma_f32_16x16x32_bf16(a1, qa[qi][1], s4[kt], 0, 0, 0);
      }
      // row max: 15 local fmax + 2 shfl (replicas at lane&15)
      float t01 = fmaxf(fmaxf(s4[0][0], s4[0][1]), fmaxf(s4[0][2], s4[0][3]));
      float t23 = fmaxf(fmaxf(s4[1][0], s4[1][1]), fmaxf(s4[1][2], s4[1][3]));
      float t45 = fmaxf(fmaxf(s4[2][0], s4[2][1]), fmaxf(s4[2][2], s4[2][3]));
      float t67 = fmaxf(fmaxf(s4[3][0], s4[3][1]), fmaxf(s4[3][2], s4[3][3]));
      float tm = fmaxf(fmaxf(t01, t23), fmaxf(t45, t67)) * C1;
      tm = fmaxf(tm, __shfl_xor(tm, 16, 64));
      tm = fmaxf(tm, __shfl_xor(tm, 32, 64));

      if (__any(tm > m_run[qi])) {
        float mn = fmaxf(m_run[qi], tm);
        float scf = __expf(m_run[qi] - mn);
        m_run[qi] = mn;
        float sc_c[4];
#pragma unroll
        for (int j = 0; j < 4; ++j) sc_c[j] = __shfl(scf, lg * 4 + j, 64);
#pragma unroll
        for (int j = 0; j < 4; ++j) {
          acc_l[qi][j] *= sc_c[j];
#pragma unroll
          for (int dt = 0; dt < 4; ++dt) o_acc[qi][dt][j] *= sc_c[j];
        }
      }

      // P = exp(s*C1 - m): key-contiguous per lane -> 4x packed b64 stores
      const float lm = m_run[qi];
#pragma unroll
      for (int kt = 0; kt < 4; ++kt) {
        float p0 = __expf(fmaf(s4[kt][0], C1, -lm));
        float p1 = __expf(fmaf(s4[kt][1], C1, -lm));
        float p2 = __expf(fmaf(s4[kt][2], C1, -lm));
        float p3 = __expf(fmaf(s4[kt][3], C1, -lm));
        unsigned long long pv =
            (unsigned long long)pack_bf2(p0, p1) |
            ((unsigned long long)pack_bf2(p2, p3) << 32);
        *(unsigned long long*)&Psw[rq * LDPS + kt * 16 + lg * 4] = pv;
      }

      // PV: A = P rows (wave-private), B = V^T rows (swizzled)
      short8 pa0 = *(const short8*)&Psw[rq * LDPS + kk8];
      short8 pa1 = *(const short8*)&Psw[rq * LDPS + 32 + kk8];
#pragma unroll
      for (int dt = 0; dt < 4; ++dt) {
        const int vrow = dt * 16 + rq, vx = (rq & 7) << 3;
        short8 v0 = *(const short8*)&Vsg[(vrow * 64 + kk8) ^ vx];
        short8 v1 = *(const short8*)&Vsg[(vrow * 64 + 32 + kk8) ^ vx];
        o_acc[qi][dt] = __builtin_amdgcn_mfma_f32_16x16x32_bf16(pa0, v0, o_acc[qi][dt], 0, 0, 0);
        o_acc[qi][dt] = __builtin_amdgcn_mfma_f32_16x16x32_bf16(pa1, v1, o_acc[qi][dt], 0, 0, 0);
      }
      acc_l[qi] = __builtin_amdgcn_mfma_f32_16x16x32_bf16(pa0, ones, acc_l[qi], 0, 0, 0);
      acc_l[qi] = __builtin_amdgcn_mfma_f32_16x16x32_bf16(pa1, ones, acc_l[qi], 0, 0, 0);
    }
    __syncthreads();
  }

  // ---- merge the two key-halves (overlay: MO over Ks+Vs, ML over Ps) ----
  float* MO = (float*)smem;            // [128][64] f32
  float* ML = (float*)(smem + 32768);  // [128][2]
  if (g == 1) {
#pragma unroll
    for (int qi = 0; qi < 2; ++qi) {
#pragma unroll
      for (int j = 0; j < 4; ++j) {
        int row = w * 32 + qi * 16 + lg * 4 + j;
        if (rq == 0) ML[row * 2 + 1] = acc_l[qi][j];
#pragma unroll
        for (int dt = 0; dt < 4; ++dt)
          MO[(size_t)row * 64 + dt * 16 + rq] = o_acc[qi][dt][j];
      }
      if (lg == 0) ML[(w * 32 + qi * 16 + rq) * 2] = m_run[qi];
    }
  }
  __syncthreads();
  if (g == 0) {
#pragma unroll
    for (int qi = 0; qi < 2; ++qi) {
      float m0c[4];
#pragma unroll
      for (int j = 0; j < 4; ++j) m0c[j] = __shfl(m_run[qi], lg * 4 + j, 64);
#pragma unroll
      for (int j = 0; j < 4; ++j) {
        int row = w * 32 + qi * 16 + lg * 4 + j;
        int r = q0 + qi * 16 + lg * 4 + j;
        float m1 = ML[row * 2 + 0], l1 = ML[row * 2 + 1];
        float m0 = m0c[j], l0 = acc_l[qi][j];
        float mx = fmaxf(m0, m1);
        float a0 = __expf(m0 - mx), a1 = __expf(m1 - mx);
        float inv = 1.0f / (l0 * a0 + l1 * a1);
#pragma unroll
        for (int dt = 0; dt < 4; ++dt) {
          float o = (o_acc[qi][dt][j] * a0 + MO[(size_t)row * 64 + dt * 16 + rq] * a1) * inv;
          Op[((size_t)b * Sc + r) * Dc + h * DKc + dt * 16 + rq] = f2bf(o);
        }
      }
    }
  }
}

// ---------------- launcher --------------------------------------------------
extern "C" void kernel_launch(void* const* d_in, const int* in_sizes, int n_in,
                              void* d_out, int out_size, void* d_ws, size_t ws_size,
                              hipStream_t stream) {
  const float* q_in = (const float*)d_in[0];
  const float* k_in = (const float*)d_in[1];
  const float* v_in = (const float*)d_in[2];
  const float* Wq = (const float*)d_in[3];
  const float* Wk = (const float*)d_in[4];
  const float* Wv = (const float*)d_in[5];
  const float* Wo = (const float*)d_in[6];

  unsigned short* wq_b = (unsigned short*)d_ws;
  unsigned short* wk_b = wq_b + Dc * Dc;
  unsigned short* wv_b = wk_b + Dc * Dc;
  unsigned short* wo_b = wv_b + Dc * Dc;
  unsigned short* qb = wo_b + Dc * Dc;
  unsigned short* kb = qb + (size_t)Mc * Dc;
  unsigned short* vb = kb + (size_t)Mc * Dc;
  unsigned short* ab = vb + (size_t)Mc * Dc;
  unsigned short* vt = ab + (size_t)Mc * Dc;  // V^T per (b): [D][S]

  dim3 cg(Dc * Dc / 4 / 256, 4);
  cast_w<<<cg, 256, 0, stream>>>(Wq, Wk, Wv, Wo, wq_b);

  dim3 gg(Dc / 128, Mc / 128);
  gemm_bt<1, 0><<<gg, 256, 0, stream>>>(q_in, wq_b, qb, Mc, Dc, Dc);
  gemm_bt<1, 0><<<gg, 256, 0, stream>>>(k_in, wk_b, kb, Mc, Dc, Dc);
  gemm_bt<1, 0><<<gg, 256, 0, stream>>>(v_in, wv_b, vb, Mc, Dc, Dc);

  dim3 tg(Sc / 64, Dc / 64, Bc);
  transpose_v<<<tg, 256, 0, stream>>>(vb, vt);

  dim3 ga(Sc / 128, Bc * Hc);  // (32, 16), 512-thread blocks
  attn_fwd<<<ga, 512, 0, stream>>>(qb, kb, vt, ab);

  gemm_bt<0, 1><<<gg, 256, 0, stream>>>(ab, wo_b, (float*)d_out, Mc, Dc, Dc);
}

// Round 6
// 220.143 us; speedup vs baseline: 1.7502x; 1.7502x over previous
//
#include <hip/hip_runtime.h>
#include <hip/hip_bf16.h>

typedef short short8 __attribute__((ext_vector_type(8)));
typedef short short4v __attribute__((ext_vector_type(4)));
typedef float floatx4 __attribute__((ext_vector_type(4)));

constexpr int Bc = 2, Sc = 4096, Dc = 512, Hc = 8, DKc = 64;
constexpr int Mc = Bc * Sc;  // 8192

static __device__ __forceinline__ unsigned short f2bf(float f) {
  unsigned int u = __builtin_bit_cast(unsigned int, f);
  unsigned int rb = ((u >> 16) & 1u) + 0x7fffu;
  return (unsigned short)((u + rb) >> 16);
}
static __device__ __forceinline__ unsigned int pack_bf2(float a, float b) {
  return (unsigned int)f2bf(a) | ((unsigned int)f2bf(b) << 16);
}

// ---------------- weight cast ------------------------------------------------
__global__ __launch_bounds__(256) void cast_w(
    const float* __restrict__ a, const float* __restrict__ b,
    const float* __restrict__ c, const float* __restrict__ d,
    unsigned short* __restrict__ out) {
  const float* srcs[4] = {a, b, c, d};
  const int m = blockIdx.y;
  const int i = (blockIdx.x * 256 + threadIdx.x) * 4;
  float4 v = *(const float4*)(srcs[m] + i);
  unsigned short t4[4] = {f2bf(v.x), f2bf(v.y), f2bf(v.z), f2bf(v.w)};
  *(short4v*)(out + (size_t)m * (Dc * Dc) + i) = *(short4v*)t4;
}

// ---------------- GEMM: Y[M,N] = X[M,K] @ W[N,K]^T ---------------------------
template <int IN_F32, int OUT_F32>
__global__ __launch_bounds__(256) void gemm_bt(
    const void* __restrict__ Xv, const unsigned short* __restrict__ Wb,
    void* __restrict__ Yv, int Mdim, int N, int K) {
  constexpr int BM = 128, BN = 128, BK = 32, LDP = 40;
  __shared__ unsigned short As[BM * LDP];
  __shared__ unsigned short Bs[BN * LDP];
  const int tid = threadIdx.x;
  const int lane = tid & 63, wid = tid >> 6;
  const int wm = wid >> 1, wn = wid & 1;
  const int bm = blockIdx.y * BM, bn = blockIdx.x * BN;
  const int rq = lane & 15, kk8 = (lane >> 4) * 8;
  const int sr = tid >> 1;
  const int sc = (tid & 1) * 16;

  floatx4 acc[4][4] = {};

  for (int k0 = 0; k0 < K; k0 += BK) {
    if (IN_F32) {
      const float* src = (const float*)Xv + (size_t)(bm + sr) * K + k0 + sc;
      unsigned short tmp[16];
#pragma unroll
      for (int i = 0; i < 4; ++i) {
        float4 v = *(const float4*)(src + i * 4);
        tmp[i * 4 + 0] = f2bf(v.x);
        tmp[i * 4 + 1] = f2bf(v.y);
        tmp[i * 4 + 2] = f2bf(v.z);
        tmp[i * 4 + 3] = f2bf(v.w);
      }
      *(short8*)&As[sr * LDP + sc] = *(short8*)&tmp[0];
      *(short8*)&As[sr * LDP + sc + 8] = *(short8*)&tmp[8];
    } else {
      const unsigned short* src =
          (const unsigned short*)Xv + (size_t)(bm + sr) * K + k0 + sc;
      *(short8*)&As[sr * LDP + sc] = *(const short8*)src;
      *(short8*)&As[sr * LDP + sc + 8] = *(const short8*)(src + 8);
    }
    const unsigned short* bsrc = Wb + (size_t)(bn + sr) * K + k0 + sc;
    *(short8*)&Bs[sr * LDP + sc] = *(const short8*)bsrc;
    *(short8*)&Bs[sr * LDP + sc + 8] = *(const short8*)(bsrc + 8);
    __syncthreads();

    short8 af[4], bfr[4];
#pragma unroll
    for (int mi = 0; mi < 4; ++mi)
      af[mi] = *(const short8*)&As[(wm * 64 + mi * 16 + rq) * LDP + kk8];
#pragma unroll
    for (int ni = 0; ni < 4; ++ni)
      bfr[ni] = *(const short8*)&Bs[(wn * 64 + ni * 16 + rq) * LDP + kk8];
#pragma unroll
    for (int mi = 0; mi < 4; ++mi)
#pragma unroll
      for (int ni = 0; ni < 4; ++ni)
        acc[mi][ni] = __builtin_amdgcn_mfma_f32_16x16x32_bf16(
            af[mi], bfr[ni], acc[mi][ni], 0, 0, 0);
    __syncthreads();
  }

#pragma unroll
  for (int mi = 0; mi < 4; ++mi)
#pragma unroll
    for (int ni = 0; ni < 4; ++ni)
#pragma unroll
      for (int j = 0; j < 4; ++j) {
        int r = bm + wm * 64 + mi * 16 + (lane >> 4) * 4 + j;
        int c = bn + wn * 64 + ni * 16 + rq;
        float v = acc[mi][ni][j];
        if (OUT_F32)
          ((float*)Yv)[(size_t)r * N + c] = v;
        else
          ((unsigned short*)Yv)[(size_t)r * N + c] = f2bf(v);
      }
}

// ---------------- V transpose: vt[b][c][s] = vb[b][s][c] ---------------------
__global__ __launch_bounds__(256) void transpose_v(
    const unsigned short* __restrict__ vb, unsigned short* __restrict__ vt) {
  constexpr int LDT = 65;
  __shared__ unsigned short T[64 * LDT];
  const int tid = threadIdx.x;
  const int s0 = blockIdx.x * 64, c0 = blockIdx.y * 64, b = blockIdx.z;
  const int r = tid >> 2, cs = (tid & 3) * 16;
  const unsigned short* src = vb + ((size_t)b * Sc + s0 + r) * Dc + c0 + cs;
  *(short8*)&T[r * LDT + cs] = *(const short8*)src;
  *(short8*)&T[r * LDT + cs + 8] = *(const short8*)(src + 8);
  __syncthreads();
  unsigned short* dst = vt + ((size_t)b * Dc + c0 + r) * Sc + s0 + cs;
  unsigned short tmp[16];
#pragma unroll
  for (int j = 0; j < 16; ++j) tmp[j] = T[(cs + j) * LDT + r];
  *(short8*)dst = *(short8*)&tmp[0];
  *(short8*)(dst + 8) = *(short8*)&tmp[8];
}

// ---------------- flash attention (k-split, swapped QK^T) --------------------
// 512 threads = 8 waves; group g = key-half; wave w owns 32 q-rows.
// Swapped QK^T: s = mfma(K_frag, Q_frag) -> lane holds 16 scores for q=lane&15.
// launch_bounds min-waves = 4 (NOT 6): 6 caps VGPR at ~85 and forces
// accumulator spills to scratch (R5: 800MB WRITE_SIZE, 1.6x slowdown).
__global__ __launch_bounds__(512, 4) void attn_fwd(
    const unsigned short* __restrict__ Qp, const unsigned short* __restrict__ Kp,
    const unsigned short* __restrict__ Vtp, unsigned short* __restrict__ Op) {
  constexpr int KB = 64, LDPS = 72;
  // LDS map (bytes): Ks [0,16384) 2g x [64][64] swz; Vs [16384,32768) same;
  // Ps [32768,51200) 2g x 4w x [16][72]. Merge overlay: MO f32[128][64] @0,
  // ML f32[128][2] @32768.
  __shared__ unsigned char smem[51200];
  unsigned short* KsB = (unsigned short*)smem;
  unsigned short* VsB = (unsigned short*)(smem + 16384);
  unsigned short* PsB = (unsigned short*)(smem + 32768);

  const int tid = threadIdx.x, lane = tid & 63, wid = tid >> 6;
  const int g = wid >> 2, w = wid & 3;
  const int b = blockIdx.y >> 3, h = blockIdx.y & 7;
  const int q0 = blockIdx.x * 128 + w * 32;
  const int rq = lane & 15, lg = lane >> 4, kk8 = lg * 8;

  unsigned short* Ksg = KsB + g * 4096;
  unsigned short* Vsg = VsB + g * 4096;
  unsigned short* Psw = PsB + (g * 4 + w) * (16 * LDPS);

  const unsigned short* Qb = Qp + ((size_t)b * Sc) * Dc + h * DKc;
  const unsigned short* Kb = Kp + ((size_t)b * Sc) * Dc + h * DKc;
  const unsigned short* Vh = Vtp + ((size_t)b * Dc + h * DKc) * Sc;

  // Q as B-fragment: col=lane&15=q, k=(lane>>4)*8+j  (row-wise load)
  short8 qa[2][2];
#pragma unroll
  for (int qi = 0; qi < 2; ++qi)
#pragma unroll
    for (int c = 0; c < 2; ++c)
      qa[qi][c] = *(const short8*)(Qb + (size_t)(q0 + qi * 16 + rq) * Dc + c * 32 + kk8);

  floatx4 o_acc[2][4] = {};
  floatx4 acc_l[2] = {};
  float m_run[2] = {-1e30f, -1e30f};  // per-lane, q = lane&15 (x4 replicas)

  short8 ones;
#pragma unroll
  for (int j = 0; j < 8; ++j) ones[j] = (short)0x3F80;

  const float C1 = 0.125f;  // 1/sqrt(64)

  // staging map: 256 threads/group stage 64 rows x 64 cols, XOR granule swizzle
  const int u = tid & 255;
  const int sr = u >> 2, sc16 = (u & 3) * 16;
  const int st0 = (sr * 64 + sc16) ^ ((sr & 7) << 3);
  const int st1 = (sr * 64 + sc16 + 8) ^ ((sr & 7) << 3);

  for (int it = 0; it < Sc / 2 / KB; ++it) {
    const int k0 = g * (Sc / 2) + it * KB;
    {
      const unsigned short* ks = Kb + (size_t)(k0 + sr) * Dc + sc16;
      *(short8*)&Ksg[st0] = *(const short8*)ks;
      *(short8*)&Ksg[st1] = *(const short8*)(ks + 8);
      const unsigned short* vs = Vh + (size_t)sr * Sc + k0 + sc16;
      *(short8*)&Vsg[st0] = *(const short8*)vs;
      *(short8*)&Vsg[st1] = *(const short8*)(vs + 8);
    }
    __syncthreads();

#pragma unroll
    for (int qi = 0; qi < 2; ++qi) {
      // swapped QK^T: s4[kt][j] = S[q=rq][key = kt*16 + lg*4 + j]
      floatx4 s4[4] = {};
#pragma unroll
      for (int kt = 0; kt < 4; ++kt) {
        const int row = kt * 16 + rq, sx = (rq & 7) << 3;
        short8 a0 = *(const short8*)&Ksg[(row * 64 + kk8) ^ sx];
        short8 a1 = *(const short8*)&Ksg[(row * 64 + 32 + kk8) ^ sx];
        s4[kt] = __builtin_amdgcn_mfma_f32_16x16x32_bf16(a0, qa[qi][0], s4[kt], 0, 0, 0);
        s4[kt] = __builtin_amdgcn_mfma_f32_16x16x32_bf16(a1, qa[qi][1], s4[kt], 0, 0, 0);
      }
      // row max: 15 local fmax + 2 shfl (replicas at lane&15)
      float t01 = fmaxf(fmaxf(s4[0][0], s4[0][1]), fmaxf(s4[0][2], s4[0][3]));
      float t23 = fmaxf(fmaxf(s4[1][0], s4[1][1]), fmaxf(s4[1][2], s4[1][3]));
      float t45 = fmaxf(fmaxf(s4[2][0], s4[2][1]), fmaxf(s4[2][2], s4[2][3]));
      float t67 = fmaxf(fmaxf(s4[3][0], s4[3][1]), fmaxf(s4[3][2], s4[3][3]));
      float tm = fmaxf(fmaxf(t01, t23), fmaxf(t45, t67)) * C1;
      tm = fmaxf(tm, __shfl_xor(tm, 16, 64));
      tm = fmaxf(tm, __shfl_xor(tm, 32, 64));

      if (__any(tm > m_run[qi])) {
        float mn = fmaxf(m_run[qi], tm);
        float scf = __expf(m_run[qi] - mn);
        m_run[qi] = mn;
        float sc_c[4];
#pragma unroll
        for (int j = 0; j < 4; ++j) sc_c[j] = __shfl(scf, lg * 4 + j, 64);
#pragma unroll
        for (int j = 0; j < 4; ++j) {
          acc_l[qi][j] *= sc_c[j];
#pragma unroll
          for (int dt = 0; dt < 4; ++dt) o_acc[qi][dt][j] *= sc_c[j];
        }
      }

      // P = exp(s*C1 - m): key-contiguous per lane -> 4x packed b64 stores
      const float lm = m_run[qi];
#pragma unroll
      for (int kt = 0; kt < 4; ++kt) {
        float p0 = __expf(fmaf(s4[kt][0], C1, -lm));
        float p1 = __expf(fmaf(s4[kt][1], C1, -lm));
        float p2 = __expf(fmaf(s4[kt][2], C1, -lm));
        float p3 = __expf(fmaf(s4[kt][3], C1, -lm));
        unsigned long long pv =
            (unsigned long long)pack_bf2(p0, p1) |
            ((unsigned long long)pack_bf2(p2, p3) << 32);
        *(unsigned long long*)&Psw[rq * LDPS + kt * 16 + lg * 4] = pv;
      }

      // PV: A = P rows (wave-private), B = V^T rows (swizzled)
      short8 pa0 = *(const short8*)&Psw[rq * LDPS + kk8];
      short8 pa1 = *(const short8*)&Psw[rq * LDPS + 32 + kk8];
#pragma unroll
      for (int dt = 0; dt < 4; ++dt) {
        const int vrow = dt * 16 + rq, vx = (rq & 7) << 3;
        short8 v0 = *(const short8*)&Vsg[(vrow * 64 + kk8) ^ vx];
        short8 v1 = *(const short8*)&Vsg[(vrow * 64 + 32 + kk8) ^ vx];
        o_acc[qi][dt] = __builtin_amdgcn_mfma_f32_16x16x32_bf16(pa0, v0, o_acc[qi][dt], 0, 0, 0);
        o_acc[qi][dt] = __builtin_amdgcn_mfma_f32_16x16x32_bf16(pa1, v1, o_acc[qi][dt], 0, 0, 0);
      }
      acc_l[qi] = __builtin_amdgcn_mfma_f32_16x16x32_bf16(pa0, ones, acc_l[qi], 0, 0, 0);
      acc_l[qi] = __builtin_amdgcn_mfma_f32_16x16x32_bf16(pa1, ones, acc_l[qi], 0, 0, 0);
    }
    __syncthreads();
  }

  // ---- merge the two key-halves (overlay: MO over Ks+Vs, ML over Ps) ----
  float* MO = (float*)smem;            // [128][64] f32
  float* ML = (float*)(smem + 32768);  // [128][2]
  if (g == 1) {
#pragma unroll
    for (int qi = 0; qi < 2; ++qi) {
#pragma unroll
      for (int j = 0; j < 4; ++j) {
        int row = w * 32 + qi * 16 + lg * 4 + j;
        if (rq == 0) ML[row * 2 + 1] = acc_l[qi][j];
#pragma unroll
        for (int dt = 0; dt < 4; ++dt)
          MO[(size_t)row * 64 + dt * 16 + rq] = o_acc[qi][dt][j];
      }
      if (lg == 0) ML[(w * 32 + qi * 16 + rq) * 2] = m_run[qi];
    }
  }
  __syncthreads();
  if (g == 0) {
#pragma unroll
    for (int qi = 0; qi < 2; ++qi) {
      float m0c[4];
#pragma unroll
      for (int j = 0; j < 4; ++j) m0c[j] = __shfl(m_run[qi], lg * 4 + j, 64);
#pragma unroll
      for (int j = 0; j < 4; ++j) {
        int row = w * 32 + qi * 16 + lg * 4 + j;
        int r = q0 + qi * 16 + lg * 4 + j;
        float m1 = ML[row * 2 + 0], l1 = ML[row * 2 + 1];
        float m0 = m0c[j], l0 = acc_l[qi][j];
        float mx = fmaxf(m0, m1);
        float a0 = __expf(m0 - mx), a1 = __expf(m1 - mx);
        float inv = 1.0f / (l0 * a0 + l1 * a1);
#pragma unroll
        for (int dt = 0; dt < 4; ++dt) {
          float o = (o_acc[qi][dt][j] * a0 + MO[(size_t)row * 64 + dt * 16 + rq] * a1) * inv;
          Op[((size_t)b * Sc + r) * Dc + h * DKc + dt * 16 + rq] = f2bf(o);
        }
      }
    }
  }
}

// ---------------- launcher --------------------------------------------------
extern "C" void kernel_launch(void* const* d_in, const int* in_sizes, int n_in,
                              void* d_out, int out_size, void* d_ws, size_t ws_size,
                              hipStream_t stream) {
  const float* q_in = (const float*)d_in[0];
  const float* k_in = (const float*)d_in[1];
  const float* v_in = (const float*)d_in[2];
  const float* Wq = (const float*)d_in[3];
  const float* Wk = (const float*)d_in[4];
  const float* Wv = (const float*)d_in[5];
  const float* Wo = (const float*)d_in[6];

  unsigned short* wq_b = (unsigned short*)d_ws;
  unsigned short* wk_b = wq_b + Dc * Dc;
  unsigned short* wv_b = wk_b + Dc * Dc;
  unsigned short* wo_b = wv_b + Dc * Dc;
  unsigned short* qb = wo_b + Dc * Dc;
  unsigned short* kb = qb + (size_t)Mc * Dc;
  unsigned short* vb = kb + (size_t)Mc * Dc;
  unsigned short* ab = vb + (size_t)Mc * Dc;
  unsigned short* vt = ab + (size_t)Mc * Dc;  // V^T per (b): [D][S]

  dim3 cg(Dc * Dc / 4 / 256, 4);
  cast_w<<<cg, 256, 0, stream>>>(Wq, Wk, Wv, Wo, wq_b);

  dim3 gg(Dc / 128, Mc / 128);
  gemm_bt<1, 0><<<gg, 256, 0, stream>>>(q_in, wq_b, qb, Mc, Dc, Dc);
  gemm_bt<1, 0><<<gg, 256, 0, stream>>>(k_in, wk_b, kb, Mc, Dc, Dc);
  gemm_bt<1, 0><<<gg, 256, 0, stream>>>(v_in, wv_b, vb, Mc, Dc, Dc);

  dim3 tg(Sc / 64, Dc / 64, Bc);
  transpose_v<<<tg, 256, 0, stream>>>(vb, vt);

  dim3 ga(Sc / 128, Bc * Hc);  // (32, 16), 512-thread blocks
  attn_fwd<<<ga, 512, 0, stream>>>(qb, kb, vt, ab);

  gemm_bt<0, 1><<<gg, 256, 0, stream>>>(ab, wo_b, (float*)d_out, Mc, Dc, Dc);
}